// Round 5
// baseline (423.179 us; speedup 1.0000x reference)
//
#include <hip/hip_runtime.h>

using i32x4 = __attribute__((ext_vector_type(4))) int;

#define QMAXF 127.0f
#define EPSF 1e-8f

__device__ __forceinline__ void gload_lds16(const void* g, void* l) {
    __builtin_amdgcn_global_load_lds(
        (const __attribute__((address_space(1))) void*)g,
        (__attribute__((address_space(3))) void*)l,
        16, 0, 0);
}

// ---------------- per-row int8 quantization (rows of K=4096 f32) ----------------
__global__ __launch_bounds__(256) void quant_rows_kernel(
    const float* __restrict__ in, signed char* __restrict__ q,
    float* __restrict__ scale, int K) {
    const int row = blockIdx.x;
    const int t = threadIdx.x;
    const float4* rp = reinterpret_cast<const float4*>(in + (size_t)row * K);

    float4 v[4];
#pragma unroll
    for (int j = 0; j < 4; ++j) v[j] = rp[j * 256 + t];

    float amax = 0.f;
#pragma unroll
    for (int j = 0; j < 4; ++j) {
        amax = fmaxf(amax, fabsf(v[j].x));
        amax = fmaxf(amax, fabsf(v[j].y));
        amax = fmaxf(amax, fabsf(v[j].z));
        amax = fmaxf(amax, fabsf(v[j].w));
    }
#pragma unroll
    for (int off = 32; off > 0; off >>= 1)
        amax = fmaxf(amax, __shfl_xor(amax, off));

    __shared__ float red[4];
    if ((t & 63) == 0) red[t >> 6] = amax;
    __syncthreads();
    amax = fmaxf(fmaxf(red[0], red[1]), fmaxf(red[2], red[3]));
    amax = fmaxf(amax, EPSF);
    const float s = amax / QMAXF;   // exactly reference's scale = amax/127
    if (t == 0) scale[row] = s;

    int* qrow = reinterpret_cast<int*>(q + (size_t)row * K);
#pragma unroll
    for (int j = 0; j < 4; ++j) {
        // round-half-even (rintf) matches jnp.round; true divide matches x/scale.
        const int b0 = (int)fminf(fmaxf(rintf(v[j].x / s), -128.f), 127.f);
        const int b1 = (int)fminf(fmaxf(rintf(v[j].y / s), -128.f), 127.f);
        const int b2 = (int)fminf(fmaxf(rintf(v[j].z / s), -128.f), 127.f);
        const int b3 = (int)fminf(fmaxf(rintf(v[j].w / s), -128.f), 127.f);
        qrow[j * 256 + t] =
            (b0 & 255) | ((b1 & 255) << 8) | ((b2 & 255) << 16) | ((b3 & 255) << 24);
    }
}

// ---------------- int8 GEMM, 3-deep counted-vmcnt pipeline ----------------
// out[m][n] = dot(A[m][:], B[n][:]).  BM=256 x BN=128 tile, BKB=128 bytes/K-tile,
// 512 threads = 8 waves (4M x 2N), per-wave 64x64 via 4x4 frags of
// mfma_i32_16x16x64_i8 (2 k-steps/K-tile).  3 rotating LDS K-tile buffers
// (144 KiB): iter t issues stage loads for tile t+2, waits vmcnt(12) (tiles
// t+1,t+2 stay in flight -- never drains to 0), raw s_barrier (no implicit
// vmcnt(0) drain like __syncthreads), computes tile t.
// 16B-slot XOR swizzle (slot ^= row&7): linear LDS dest for global_load_lds +
// inverse-swizzled global source + swizzled ds_read (rule #21).  This exact
// quarter-wave read pattern measured 0 bank conflicts in round 3 (16-row
// columns; 32x32 MFMA's 32-row columns were 4-way-conflicted -- reverted).
#define BM 256
#define BN 128
#define BKB 128
#define NBUF 3
#define ABYTES (BM * BKB)        // 32768
#define BBYTES (BN * BKB)        // 16384
#define BUFSZ (ABYTES + BBYTES)  // 49152

__global__ __launch_bounds__(512, 2) void int8_gemm_kernel(
    const signed char* __restrict__ A,  // [M][K]
    const signed char* __restrict__ B,  // [N][K]
    const float* __restrict__ xscale,   // [M]
    const float* __restrict__ wscale,   // [N]
    const float* __restrict__ bias,     // [N]
    float* __restrict__ out,            // [M][N] f32
    int M, int N, int K) {
    __shared__ signed char sAB[NBUF * BUFSZ];  // 144 KiB -> 1 block/CU

    const int t = threadIdx.x;

    // XCD-aware bijective swizzle (grid = 1024, divisible by 8)
    const int nwg = gridDim.x;
    const int cpx = nwg >> 3;
    const int swz = (blockIdx.x & 7) * cpx + (blockIdx.x >> 3);
    const int tilesN = N / BN;
    const size_t m0 = (size_t)(swz / tilesN) * BM;
    const size_t n0 = (size_t)(swz % tilesN) * BN;

    // Staging map: A = 4 passes x 16B/thread (32KB), B = 2 passes (16KB).
    // Linear LDS dest (wave-uniform base + lane*16); inverse-swizzled source.
    const signed char* aSrc[4];
    int aDst[4];
    const signed char* bSrc[2];
    int bDst[2];
#pragma unroll
    for (int p = 0; p < 4; ++p) {
        const int o = p * 8192 + t * 16;
        const int row = o >> 7;            // 0..255
        const int slot = (o >> 4) & 7;
        const int gcol = (slot ^ (row & 7)) << 4;
        aDst[p] = o;
        aSrc[p] = A + (m0 + row) * (size_t)K + gcol;
    }
#pragma unroll
    for (int p = 0; p < 2; ++p) {
        const int o = p * 8192 + t * 16;
        const int row = o >> 7;            // 0..127
        const int slot = (o >> 4) & 7;
        const int gcol = (slot ^ (row & 7)) << 4;
        bDst[p] = ABYTES + o;
        bSrc[p] = B + (n0 + row) * (size_t)K + gcol;
    }

    const int lane = t & 63;
    const int l15 = lane & 15;
    const int lhi = lane >> 4;  // 0..3: 16B k-chunk within 64B MFMA k-step
    const int l7 = lane & 7;
    const int wv = t >> 6;      // 0..7
    const int wvm = wv >> 1;    // 0..3 -> rows wvm*64
    const int wvn = wv & 1;     // 0..1 -> cols wvn*64

    // ds_read offsets within a buffer: global slot s = kk*4+lhi, LDS slot s^(row&7).
    // row = (mult of 8) + l15 -> row&7 == l7.
    int aoff[2][4], boff[2][4];
#pragma unroll
    for (int kk = 0; kk < 2; ++kk)
#pragma unroll
        for (int f = 0; f < 4; ++f) {
            const int slot = ((kk << 2) | lhi) ^ l7;
            aoff[kk][f] = (wvm * 64 + f * 16 + l15) * BKB + (slot << 4);
            boff[kk][f] = ABYTES + (wvn * 64 + f * 16 + l15) * BKB + (slot << 4);
        }

    i32x4 acc[4][4];
    const i32x4 zero = {0, 0, 0, 0};
#pragma unroll
    for (int i = 0; i < 4; ++i)
#pragma unroll
        for (int j = 0; j < 4; ++j) acc[i][j] = zero;

    const int nt = K / BKB;  // 32

    // Prologue: stage tile 0 -> buf0, tile 1 -> buf1 (12 loads in flight)
#pragma unroll
    for (int p = 0; p < 4; ++p) gload_lds16(aSrc[p], sAB + aDst[p]);
#pragma unroll
    for (int p = 0; p < 2; ++p) gload_lds16(bSrc[p], sAB + bDst[p]);
#pragma unroll
    for (int p = 0; p < 4; ++p) gload_lds16(aSrc[p] + BKB, sAB + BUFSZ + aDst[p]);
#pragma unroll
    for (int p = 0; p < 2; ++p) gload_lds16(bSrc[p] + BKB, sAB + BUFSZ + bDst[p]);

    int cbuf = 0;  // buffer holding tile kt
    int sbuf = 2;  // buffer for tile kt+2
    for (int kt = 0; kt < nt; ++kt) {
        // Issue next-next tile's 6 loads early (T14): dest buf (kt+2)%3 held
        // tile kt-1, whose reads finished at iter kt-1's end barrier.
        if (kt + 2 < nt) {
            const size_t ko = (size_t)(kt + 2) * BKB;
            const int sb = sbuf * BUFSZ;
#pragma unroll
            for (int p = 0; p < 4; ++p) gload_lds16(aSrc[p] + ko, sAB + sb + aDst[p]);
#pragma unroll
            for (int p = 0; p < 2; ++p) gload_lds16(bSrc[p] + ko, sAB + sb + bDst[p]);
        }
        // Counted wait: tile kt landed; tiles kt+1,kt+2 (12 loads) stay in flight.
        if (kt < nt - 2)
            asm volatile("s_waitcnt vmcnt(12)" ::: "memory");
        else if (kt == nt - 2)
            asm volatile("s_waitcnt vmcnt(6)" ::: "memory");
        else
            asm volatile("s_waitcnt vmcnt(0)" ::: "memory");
        __builtin_amdgcn_s_barrier();   // all waves' tile-kt loads landed
        asm volatile("" ::: "memory");  // pin ds_reads below the barrier

        const signed char* base = sAB + cbuf * BUFSZ;
#pragma unroll
        for (int kk = 0; kk < 2; ++kk) {
            i32x4 af[4], bf[4];
#pragma unroll
            for (int f = 0; f < 4; ++f)
                af[f] = *reinterpret_cast<const i32x4*>(base + aoff[kk][f]);
#pragma unroll
            for (int f = 0; f < 4; ++f)
                bf[f] = *reinterpret_cast<const i32x4*>(base + boff[kk][f]);
            __builtin_amdgcn_s_setprio(1);
#pragma unroll
            for (int i = 0; i < 4; ++i)
#pragma unroll
                for (int j = 0; j < 4; ++j)
                    acc[i][j] = __builtin_amdgcn_mfma_i32_16x16x64_i8(
                        af[i], bf[j], acc[i][j], 0, 0, 0);
            __builtin_amdgcn_s_setprio(0);
        }

        asm volatile("" ::: "memory");  // pin reads above the barrier
        __builtin_amdgcn_s_barrier();   // reads done before buf reuse at kt+3
        cbuf = (cbuf == NBUF - 1) ? 0 : cbuf + 1;
        sbuf = (sbuf == NBUF - 1) ? 0 : sbuf + 1;
    }

    // Epilogue: 16x16 C/D layout: col = lane&15, row = (lane>>4)*4 + reg
#pragma unroll
    for (int f = 0; f < 4; ++f) {
        float xsv[4];
#pragma unroll
        for (int r = 0; r < 4; ++r)
            xsv[r] = xscale[m0 + wvm * 64 + f * 16 + lhi * 4 + r];
#pragma unroll
        for (int g = 0; g < 4; ++g) {
            const int n = (int)n0 + wvn * 64 + g * 16 + l15;
            const float wsv = wscale[n];
            const float bv = bias[n];
#pragma unroll
            for (int r = 0; r < 4; ++r) {
                const size_t m = m0 + wvm * 64 + f * 16 + lhi * 4 + r;
                out[m * (size_t)N + n] = ((float)acc[f][g][r] * xsv[r]) * wsv + bv;
            }
        }
    }
}

extern "C" void kernel_launch(void* const* d_in, const int* in_sizes, int n_in,
                              void* d_out, int out_size, void* d_ws, size_t ws_size,
                              hipStream_t stream) {
    const float* x = (const float*)d_in[0];     // (B,S,I) f32
    const float* w = (const float*)d_in[1];     // (O,I) f32
    const float* bias = (const float*)d_in[2];  // (O,) f32
    float* out = (float*)d_out;

    const int O = in_sizes[2];            // 4096
    const int I = in_sizes[1] / O;        // 4096
    const int M = in_sizes[0] / I;        // 8192 (= B*S)

    // workspace: x_q | w_q | x_scale | w_scale (~50.4 MB)
    char* ws = (char*)d_ws;
    signed char* xq = (signed char*)ws;
    signed char* wq = xq + (size_t)M * I;
    float* xs = (float*)(wq + (size_t)O * I);
    float* wsc = xs + M;

    quant_rows_kernel<<<M, 256, 0, stream>>>(x, xq, xs, I);
    quant_rows_kernel<<<O, 256, 0, stream>>>(w, wq, wsc, I);

    const int grid = (M / BM) * (O / BN);  // 32 * 32 = 1024
    int8_gemm_kernel<<<grid, 512, 0, stream>>>(xq, wq, xs, wsc, bias, out,
                                               M, O, I);
}